// Round 1
// baseline (932.639 us; speedup 1.0000x reference)
//
#include <hip/hip_runtime.h>
#include <cstdint>
#include <cstddef>

#define NN 50000
#define NE 800000
#define HID 128
#define NGRAPH 64
#define NCLASS 10
#define LHID 3

// 1/sqrt(1+1e-5), computed in double, rounded to f32
static constexpr float BN_INV = 0.9999950000374996f;

// ---------------- graph build ----------------

__global__ void k_deg(const int* __restrict__ ei, int* __restrict__ deg) {
    int e = blockIdx.x * 256 + threadIdx.x;
    if (e < NE) atomicAdd(&deg[ei[NE + e]], 1);
}

__global__ void k_dinv(const int* __restrict__ deg, float* __restrict__ dinv) {
    int i = blockIdx.x * 256 + threadIdx.x;
    if (i < NN) dinv[i] = rsqrtf((float)(deg[i] + 1));  // +1 self-loop
}

__global__ void k_scan1(const int* __restrict__ deg, int* __restrict__ bsum) {
    __shared__ int s[256];
    int i = blockIdx.x * 256 + threadIdx.x;
    s[threadIdx.x] = (i < NN) ? deg[i] : 0;
    __syncthreads();
    for (int o = 128; o > 0; o >>= 1) {
        if (threadIdx.x < o) s[threadIdx.x] += s[threadIdx.x + o];
        __syncthreads();
    }
    if (threadIdx.x == 0) bsum[blockIdx.x] = s[0];
}

__global__ void k_scan2(int* __restrict__ bsum, int nb) {
    if (threadIdx.x == 0 && blockIdx.x == 0) {
        int run = 0;
        for (int b = 0; b < nb; ++b) { int v = bsum[b]; bsum[b] = run; run += v; }
    }
}

__global__ void k_scan3(const int* __restrict__ deg, const int* __restrict__ bsum,
                        int* __restrict__ rowptr) {
    __shared__ int s[256];
    int i = blockIdx.x * 256 + threadIdx.x;
    int v = (i < NN) ? deg[i] : 0;
    s[threadIdx.x] = v;
    __syncthreads();
    for (int o = 1; o < 256; o <<= 1) {
        int tv = (threadIdx.x >= o) ? s[threadIdx.x - o] : 0;
        __syncthreads();
        s[threadIdx.x] += tv;
        __syncthreads();
    }
    if (i < NN) rowptr[i] = bsum[blockIdx.x] + s[threadIdx.x] - v;  // exclusive
}

__global__ void k_fill(const int* __restrict__ ei, const int* __restrict__ rowptr,
                       int* __restrict__ cursor, const float* __restrict__ dinv,
                       int* __restrict__ col, float* __restrict__ cfv) {
    int e = blockIdx.x * 256 + threadIdx.x;
    if (e >= NE) return;
    int s = ei[e];
    int d = ei[NE + e];
    int p = rowptr[d] + atomicAdd(&cursor[d], 1);
    col[p] = s;
    cfv[p] = dinv[s];
}

// ---------------- dense GEMM: C1 = A @ B1 (+ C2 = A @ B2) ----------------
// A: [NN,128] f32 row-major, B: [128, 128] row-major.
// tile: 64 rows x 128*NB cols, K chunked by 32. 256 threads.
// thread (tx in [0,32), ty in [0,8)): 8 rows x 4 cols per B.

template <int NB>
__global__ __launch_bounds__(256) void k_gemm(const float* __restrict__ A,
                                              const float* __restrict__ B1,
                                              const float* __restrict__ B2,
                                              float* __restrict__ C1,
                                              float* __restrict__ C2) {
    __shared__ float As[32][68];          // transposed: As[kk][row]
    __shared__ float Bs[32][128 * NB];    // Bs[kk][col], B2 cols at +128
    const int tid = threadIdx.x;
    const int tx = tid & 31;
    const int ty = tid >> 5;
    const int rowBase = blockIdx.x * 64;

    float acc[8][4 * NB];
#pragma unroll
    for (int i = 0; i < 8; ++i)
#pragma unroll
        for (int j = 0; j < 4 * NB; ++j) acc[i][j] = 0.0f;

    for (int kc = 0; kc < 4; ++kc) {
        // stage A chunk (64 rows x 32 k), transposed into LDS
#pragma unroll
        for (int it = 0; it < 2; ++it) {
            int i = tid + it * 256;           // [0,512) float4 index
            int row = i >> 3;
            int k4 = i & 7;
            int rr = rowBase + row;
            float4 v = make_float4(0.f, 0.f, 0.f, 0.f);
            if (rr < NN) v = *(const float4*)&A[(size_t)rr * 128 + kc * 32 + k4 * 4];
            As[k4 * 4 + 0][row] = v.x;
            As[k4 * 4 + 1][row] = v.y;
            As[k4 * 4 + 2][row] = v.z;
            As[k4 * 4 + 3][row] = v.w;
        }
        // stage B chunk(s): 32 x 128*NB floats
#pragma unroll
        for (int it = 0; it < 4 * NB; ++it) {
            int j = tid + it * 256;                      // float4 index, [0, 1024*NB)
            int kk = j / (32 * NB);
            int c4 = j % (32 * NB);
            int c = c4 * 4;
            float4 v;
            if (NB == 2 && c >= 128)
                v = *(const float4*)&B2[(kc * 32 + kk) * 128 + (c - 128)];
            else
                v = *(const float4*)&B1[(kc * 32 + kk) * 128 + c];
            *(float4*)&Bs[kk][c] = v;
        }
        __syncthreads();

#pragma unroll
        for (int kk = 0; kk < 32; ++kk) {
            float4 a0 = *(const float4*)&As[kk][ty * 8];
            float4 a1 = *(const float4*)&As[kk][ty * 8 + 4];
            float a[8] = {a0.x, a0.y, a0.z, a0.w, a1.x, a1.y, a1.z, a1.w};
            float b[4 * NB];
            *(float4*)&b[0] = *(const float4*)&Bs[kk][tx * 4];
            if (NB == 2) *(float4*)&b[4] = *(const float4*)&Bs[kk][128 + tx * 4];
#pragma unroll
            for (int ri = 0; ri < 8; ++ri)
#pragma unroll
                for (int j = 0; j < 4 * NB; ++j) acc[ri][j] += a[ri] * b[j];
        }
        __syncthreads();
    }

#pragma unroll
    for (int ri = 0; ri < 8; ++ri) {
        int rr = rowBase + ty * 8 + ri;
        if (rr < NN) {
            float4 v1 = make_float4(acc[ri][0], acc[ri][1], acc[ri][2], acc[ri][3]);
            *(float4*)&C1[(size_t)rr * 128 + tx * 4] = v1;
            if (NB == 2) {
                float4 v2 = make_float4(acc[ri][4], acc[ri][5], acc[ri][6], acc[ri][7]);
                *(float4*)&C2[(size_t)rr * 128 + tx * 4] = v2;
            }
        }
    }
}

// ---------------- SpMM + epilogue (bias [+res] + BN + ReLU) ----------------
// one wave per node; lane handles 2 features (float2).

template <bool RES>
__global__ __launch_bounds__(256) void k_spmm(const float* __restrict__ t,
                                              const float* __restrict__ r,
                                              const int* __restrict__ rowptr,
                                              const int* __restrict__ deg,
                                              const int* __restrict__ col,
                                              const float* __restrict__ cfv,
                                              const float* __restrict__ dinv,
                                              const float* __restrict__ bias,
                                              const float* __restrict__ gamma,
                                              const float* __restrict__ beta,
                                              float* __restrict__ hout) {
    int lane = threadIdx.x & 63;
    int node = blockIdx.x * 4 + (threadIdx.x >> 6);
    if (node >= NN) return;
    int f = lane * 2;
    int start = rowptr[node];
    int cnt = deg[node];
    float ax = 0.f, ay = 0.f;
    for (int p = 0; p < cnt; ++p) {
        int s = col[start + p];
        float w = cfv[start + p];
        float2 v = *(const float2*)&t[s * 128 + f];
        ax += w * v.x;
        ay += w * v.y;
    }
    float di = dinv[node];
    float2 tv = *(const float2*)&t[node * 128 + f];
    float2 bv = *(const float2*)&bias[f];
    float cx = di * ax + di * di * tv.x + bv.x;
    float cy = di * ay + di * di * tv.y + bv.y;
    if (RES) {
        float2 rv = *(const float2*)&r[node * 128 + f];
        cx += rv.x;
        cy += rv.y;
    }
    float2 gv = *(const float2*)&gamma[f];
    float2 ev = *(const float2*)&beta[f];
    float ox = fmaxf(cx * (BN_INV * gv.x) + ev.x, 0.f);
    float oy = fmaxf(cy * (BN_INV * gv.y) + ev.y, 0.f);
    *(float2*)&hout[node * 128 + f] = make_float2(ox, oy);
}

// ---------------- pooling (segment max over sorted batch) ----------------

__device__ inline int lbound(const int* __restrict__ b, int v) {
    int lo = 0, hi = NN;
    while (lo < hi) {
        int mid = (lo + hi) >> 1;
        if (b[mid] < v) lo = mid + 1; else hi = mid;
    }
    return lo;
}

__global__ void k_pool(const float* __restrict__ h, const int* __restrict__ batch,
                       float* __restrict__ pooled) {
    __shared__ int sLo, sHi;
    int g = blockIdx.x >> 2;
    int ch = blockIdx.x & 3;
    if (threadIdx.x == 0) {
        sLo = lbound(batch, g);
        sHi = lbound(batch, g + 1);
    }
    __syncthreads();
    int lo = sLo, hi = sHi;
    int len = hi - lo;
    int per = (len + 3) >> 2;
    int s = lo + ch * per;
    int e = min(s + per, hi);
    float m = 0.0f;  // h >= 0 post-ReLU, so 0 is the identity for non-empty segs
    for (int i = s; i < e; ++i) m = fmaxf(m, h[(size_t)i * 128 + threadIdx.x]);
    if (s < e) atomicMax((unsigned int*)&pooled[g * 128 + threadIdx.x], __float_as_uint(m));
}

// ---------------- MLP head ----------------

__global__ void k_head(const float* __restrict__ pooled, const float* __restrict__ mW1,
                       const float* __restrict__ mb1, const float* __restrict__ mW2,
                       const float* __restrict__ mb2, float* __restrict__ out) {
    __shared__ float p[128];
    __shared__ float z[128];
    int g = blockIdx.x;
    int j = threadIdx.x;  // 128 threads
    p[j] = pooled[g * 128 + j];
    __syncthreads();
    float a = mb1[j];
#pragma unroll 8
    for (int k = 0; k < 128; ++k) a += p[k] * mW1[k * 128 + j];
    z[j] = fmaxf(a, 0.f);
    __syncthreads();
    if (j < NCLASS) {
        float o = mb2[j];
#pragma unroll 8
        for (int k = 0; k < 128; ++k) o += z[k] * mW2[k * NCLASS + j];
        out[g * NCLASS + j] = o;
    }
}

// ---------------- launcher ----------------

extern "C" void kernel_launch(void* const* d_in, const int* in_sizes, int n_in,
                              void* d_out, int out_size, void* d_ws, size_t ws_size,
                              hipStream_t stream) {
    const float* x   = (const float*)d_in[0];
    const int*   ei  = (const int*)d_in[1];
    const int* batch = (const int*)d_in[2];
    const float* W0  = (const float*)d_in[3];
    const float* b0  = (const float*)d_in[4];
    const float* g0  = (const float*)d_in[5];
    const float* be0 = (const float*)d_in[6];
    const float* Wh  = (const float*)d_in[7];
    const float* bh  = (const float*)d_in[8];
    const float* gh  = (const float*)d_in[9];
    const float* beh = (const float*)d_in[10];
    const float* Rh  = (const float*)d_in[11];
    const float* mW1 = (const float*)d_in[12];
    const float* mb1 = (const float*)d_in[13];
    const float* mW2 = (const float*)d_in[14];
    const float* mb2 = (const float*)d_in[15];
    float* out = (float*)d_out;

    char* ws = (char*)d_ws;
    size_t off = 0;
    auto alloc = [&](size_t bytes) -> void* {
        void* p = ws + off;
        off += (bytes + 255) & ~(size_t)255;
        return p;
    };
    int*   deg    = (int*)alloc((size_t)NN * 4);
    int*   rowptr = (int*)alloc((size_t)NN * 4);
    int*   cursor = (int*)alloc((size_t)NN * 4);
    float* dinv   = (float*)alloc((size_t)NN * 4);
    int*   bsum   = (int*)alloc(256 * 4);
    int*   col    = (int*)alloc((size_t)NE * 4);
    float* cfv    = (float*)alloc((size_t)NE * 4);
    float* t      = (float*)alloc((size_t)NN * HID * 4);
    float* rbuf   = (float*)alloc((size_t)NN * HID * 4);
    float* hA     = (float*)alloc((size_t)NN * HID * 4);
    float* hB     = (float*)alloc((size_t)NN * HID * 4);
    float* pooled = (float*)alloc((size_t)NGRAPH * HID * 4);

    hipMemsetAsync(deg, 0, (size_t)NN * 4, stream);
    hipMemsetAsync(cursor, 0, (size_t)NN * 4, stream);
    hipMemsetAsync(pooled, 0, (size_t)NGRAPH * HID * 4, stream);

    k_deg<<<NE / 256, 256, 0, stream>>>(ei, deg);
    k_dinv<<<(NN + 255) / 256, 256, 0, stream>>>(deg, dinv);
    k_scan1<<<(NN + 255) / 256, 256, 0, stream>>>(deg, bsum);
    k_scan2<<<1, 64, 0, stream>>>(bsum, (NN + 255) / 256);
    k_scan3<<<(NN + 255) / 256, 256, 0, stream>>>(deg, bsum, rowptr);
    k_fill<<<NE / 256, 256, 0, stream>>>(ei, rowptr, cursor, dinv, col, cfv);

    const int gemmGrid = (NN + 63) / 64;
    const int spmmGrid = (NN + 3) / 4;

    // initial block: t = x @ W0 ; hA = bn_relu(agg(t) + b0)
    k_gemm<1><<<gemmGrid, 256, 0, stream>>>(x, W0, nullptr, t, nullptr);
    k_spmm<false><<<spmmGrid, 256, 0, stream>>>(t, nullptr, rowptr, deg, col, cfv,
                                                dinv, b0, g0, be0, hA);

    // residual blocks
    float* bufs[2] = {hA, hB};
    int cur = 0;
    for (int i = 0; i < LHID; ++i) {
        const float* hin = bufs[cur];
        float* hout = bufs[cur ^ 1];
        k_gemm<2><<<gemmGrid, 256, 0, stream>>>(hin, Wh + (size_t)i * HID * HID,
                                                Rh + (size_t)i * HID * HID, t, rbuf);
        k_spmm<true><<<spmmGrid, 256, 0, stream>>>(t, rbuf, rowptr, deg, col, cfv,
                                                   dinv, bh + i * HID, gh + i * HID,
                                                   beh + i * HID, hout);
        cur ^= 1;
    }

    k_pool<<<NGRAPH * 4, 128, 0, stream>>>(bufs[cur], batch, pooled);
    k_head<<<NGRAPH, 128, 0, stream>>>(pooled, mW1, mb1, mW2, mb2, out);
}

// Round 2
// 734.745 us; speedup vs baseline: 1.2693x; 1.2693x over previous
//
#include <hip/hip_runtime.h>
#include <cstdint>
#include <cstddef>

#define NN 50000
#define NE 800000
#define HID 128
#define NGRAPH 64
#define NCLASS 10
#define LHID 3

// row-blocks of 16 rows: 50000/16 = 3125 exact; GEMM grid covers 391*8 = 3128
#define ROWBLK 3125
#define ROWBLK_PAD 3128
#define GEMM_GRID 391

// 1/sqrt(1+1e-5), computed in double, rounded to f32
static constexpr float BN_INV = 0.9999950000374996f;

typedef __attribute__((ext_vector_type(8))) __bf16 bf16x8;
typedef __attribute__((ext_vector_type(4))) float floatx4;

// ---------------- bf16 split helpers ----------------

__device__ __forceinline__ unsigned short f32_to_bf16_rne(float f) {
    unsigned int u = __float_as_uint(f);
    unsigned int r = (u + 0x7FFFu + ((u >> 16) & 1u)) >> 16;
    return (unsigned short)r;
}
__device__ __forceinline__ float bf16_to_f32(unsigned short h) {
    return __uint_as_float(((unsigned int)h) << 16);
}

__device__ __forceinline__ void gl2lds16(const void* g, void* l) {
    __builtin_amdgcn_global_load_lds((__attribute__((address_space(1))) void*)g,
                                     (__attribute__((address_space(3))) void*)l,
                                     16, 0, 0);
}

// ---------------- graph build ----------------

__global__ void k_deg(const int* __restrict__ ei, int* __restrict__ deg) {
    int e = blockIdx.x * 256 + threadIdx.x;
    if (e < NE) atomicAdd(&deg[ei[NE + e]], 1);
}

__global__ void k_dinv(const int* __restrict__ deg, float* __restrict__ dinv) {
    int i = blockIdx.x * 256 + threadIdx.x;
    if (i < NN) dinv[i] = rsqrtf((float)(deg[i] + 1));  // +1 self-loop
}

__global__ void k_scan1(const int* __restrict__ deg, int* __restrict__ bsum) {
    __shared__ int s[256];
    int i = blockIdx.x * 256 + threadIdx.x;
    s[threadIdx.x] = (i < NN) ? deg[i] : 0;
    __syncthreads();
    for (int o = 128; o > 0; o >>= 1) {
        if (threadIdx.x < o) s[threadIdx.x] += s[threadIdx.x + o];
        __syncthreads();
    }
    if (threadIdx.x == 0) bsum[blockIdx.x] = s[0];
}

__global__ void k_scan2(int* __restrict__ bsum, int nb) {
    if (threadIdx.x == 0 && blockIdx.x == 0) {
        int run = 0;
        for (int b = 0; b < nb; ++b) { int v = bsum[b]; bsum[b] = run; run += v; }
    }
}

__global__ void k_scan3(const int* __restrict__ deg, const int* __restrict__ bsum,
                        int* __restrict__ rowptr) {
    __shared__ int s[256];
    int i = blockIdx.x * 256 + threadIdx.x;
    int v = (i < NN) ? deg[i] : 0;
    s[threadIdx.x] = v;
    __syncthreads();
    for (int o = 1; o < 256; o <<= 1) {
        int tv = (threadIdx.x >= o) ? s[threadIdx.x - o] : 0;
        __syncthreads();
        s[threadIdx.x] += tv;
        __syncthreads();
    }
    if (i < NN) rowptr[i] = bsum[blockIdx.x] + s[threadIdx.x] - v;  // exclusive
}

__global__ void k_fill(const int* __restrict__ ei, const int* __restrict__ rowptr,
                       int* __restrict__ cursor, const float* __restrict__ dinv,
                       int* __restrict__ col, float* __restrict__ cfv) {
    int e = blockIdx.x * 256 + threadIdx.x;
    if (e >= NE) return;
    int s = ei[e];
    int d = ei[NE + e];
    int p = rowptr[d] + atomicAdd(&cursor[d], 1);
    col[p] = s;
    cfv[p] = dinv[s];
}

// ---------------- converters: fp32 -> swizzled bf16 hi/lo ----------------
// A-operand fragment layout per (rowBlock of 16 m) x (kblk of 32 k) block:
//   lane = ((k>>3)&3)*16 + (m&15), holds 8 consecutive k (16 B).
// Flat: ((rowBlock*4 + kblk)*64 + lane)*8 elements.

__global__ void k_convA(const float* __restrict__ src, unsigned short* __restrict__ hi,
                        unsigned short* __restrict__ lo) {
    int u = blockIdx.x * 256 + threadIdx.x;  // 0 .. 800000-1 (one 16B output unit each)
    int lane = u & 63;
    int blk = u >> 6;
    int kblk = blk & 3;
    int rowBlock = blk >> 2;
    int m = rowBlock * 16 + (lane & 15);
    int k = kblk * 32 + (lane >> 4) * 8;
    const float4* p = (const float4*)&src[(size_t)m * 128 + k];
    float4 v0 = p[0];
    float4 v1 = p[1];
    float vals[8] = {v0.x, v0.y, v0.z, v0.w, v1.x, v1.y, v1.z, v1.w};
    union { unsigned short s[8]; uint4 v; } H, L;
#pragma unroll
    for (int j = 0; j < 8; ++j) {
        unsigned short h = f32_to_bf16_rne(vals[j]);
        H.s[j] = h;
        L.s[j] = f32_to_bf16_rne(vals[j] - bf16_to_f32(h));
    }
    *(uint4*)&hi[(size_t)u * 8] = H.v;
    *(uint4*)&lo[(size_t)u * 8] = L.v;
}

// B-operand: source W is [k][n] row-major (128x128). Fragment layout per
// (nBlock of 16 n) x (kblk of 32 k): lane = ((k>>3)&3)*16 + (n&15), 8 consecutive k.
// 7 matrices: 0 = W0, 1..3 = Wh[i], 4..6 = Rh[i]; each 16384 elems in output.

__global__ void k_convB(const float* __restrict__ W0, const float* __restrict__ Wh,
                        const float* __restrict__ Rh, unsigned short* __restrict__ hi,
                        unsigned short* __restrict__ lo) {
    int mat = blockIdx.y;
    const float* src = (mat == 0) ? W0
                     : (mat <= 3) ? (Wh + (size_t)(mat - 1) * 16384)
                                  : (Rh + (size_t)(mat - 4) * 16384);
    int u = blockIdx.x * 256 + threadIdx.x;  // 0..2047
    int lane = u & 63;
    int blk = u >> 6;
    int kblk = blk & 3;
    int nb = blk >> 2;
    int n = nb * 16 + (lane & 15);
    int k = kblk * 32 + (lane >> 4) * 8;
    union { unsigned short s[8]; uint4 v; } H, L;
#pragma unroll
    for (int j = 0; j < 8; ++j) {
        float f = src[(size_t)(k + j) * 128 + n];
        unsigned short h = f32_to_bf16_rne(f);
        H.s[j] = h;
        L.s[j] = f32_to_bf16_rne(f - bf16_to_f32(h));
    }
    size_t base = (size_t)mat * 16384 + (size_t)u * 8;
    *(uint4*)&hi[base] = H.v;
    *(uint4*)&lo[base] = L.v;
}

// ---------------- MFMA GEMM: C = A @ B, split-bf16 3-product ----------------
// A: swizzled hi/lo [ROWBLK_PAD*4*512], B: swizzled hi/lo 16384 elems (one matrix).
// Block: 128 rows x 128 cols, 256 threads (4 waves, 2x2), wave tile 64x64 = 4x4
// mfma_f32_16x16x32_bf16 tiles. K = 128 in 2 chunks of 64.

__global__ __launch_bounds__(256, 2) void k_gemm_mfma(
    const unsigned short* __restrict__ Ahi, const unsigned short* __restrict__ Alo,
    const unsigned short* __restrict__ Bhi, const unsigned short* __restrict__ Blo,
    float* __restrict__ C) {
    __shared__ unsigned short lds[4 * 8192];  // 64 KB
    unsigned short* AhiS = lds;
    unsigned short* AloS = lds + 8192;
    unsigned short* BhiS = lds + 16384;
    unsigned short* BloS = lds + 24576;

    const int tid = threadIdx.x;
    const int wave = tid >> 6;
    const int lane = tid & 63;
    const int wm = wave & 1;
    const int wn = wave >> 1;
    const int rb0 = blockIdx.x * 8;

    floatx4 acc[4][4];
    floatx4 zero = {0.f, 0.f, 0.f, 0.f};
#pragma unroll
    for (int i = 0; i < 4; ++i)
#pragma unroll
        for (int j = 0; j < 4; ++j) acc[i][j] = zero;

    for (int kc = 0; kc < 2; ++kc) {
#pragma unroll
        for (int it = 0; it < 4; ++it) {
            int b = it * 4 + wave;        // 0..15 : rb = b>>1, kb = b&1
            int rb = b >> 1;
            int kb = b & 1;
            size_t aOff = ((size_t)(rb0 + rb) * 4 + kc * 2 + kb) * 512 + (size_t)lane * 8;
            size_t bOff = ((size_t)rb * 4 + kc * 2 + kb) * 512 + (size_t)lane * 8;
            int ldsOff = b * 512;  // wave-uniform base; HW adds lane*16B
            gl2lds16(Ahi + aOff, AhiS + ldsOff);
            gl2lds16(Alo + aOff, AloS + ldsOff);
            gl2lds16(Bhi + bOff, BhiS + ldsOff);
            gl2lds16(Blo + bOff, BloS + ldsOff);
        }
        __syncthreads();

#pragma unroll
        for (int kb = 0; kb < 2; ++kb) {
            bf16x8 aH[4], aL[4], bH[4], bL[4];
#pragma unroll
            for (int t = 0; t < 4; ++t) {
                aH[t] = *(const bf16x8*)(AhiS + ((wm * 4 + t) * 2 + kb) * 512 + lane * 8);
                bH[t] = *(const bf16x8*)(BhiS + ((wn * 4 + t) * 2 + kb) * 512 + lane * 8);
            }
#pragma unroll
            for (int tm = 0; tm < 4; ++tm)
#pragma unroll
                for (int tn = 0; tn < 4; ++tn)
                    acc[tm][tn] = __builtin_amdgcn_mfma_f32_16x16x32_bf16(
                        aH[tm], bH[tn], acc[tm][tn], 0, 0, 0);
#pragma unroll
            for (int t = 0; t < 4; ++t)
                bL[t] = *(const bf16x8*)(BloS + ((wn * 4 + t) * 2 + kb) * 512 + lane * 8);
#pragma unroll
            for (int tm = 0; tm < 4; ++tm)
#pragma unroll
                for (int tn = 0; tn < 4; ++tn)
                    acc[tm][tn] = __builtin_amdgcn_mfma_f32_16x16x32_bf16(
                        aH[tm], bL[tn], acc[tm][tn], 0, 0, 0);
#pragma unroll
            for (int t = 0; t < 4; ++t)
                aL[t] = *(const bf16x8*)(AloS + ((wm * 4 + t) * 2 + kb) * 512 + lane * 8);
#pragma unroll
            for (int tm = 0; tm < 4; ++tm)
#pragma unroll
                for (int tn = 0; tn < 4; ++tn)
                    acc[tm][tn] = __builtin_amdgcn_mfma_f32_16x16x32_bf16(
                        aL[tm], bH[tn], acc[tm][tn], 0, 0, 0);
        }
        __syncthreads();
    }

    // epilogue: C/D layout col = lane&15, row = (lane>>4)*4 + r
    const int quad = lane >> 4;
    const int col0 = lane & 15;
    const int rowBase = rb0 * 16 + wm * 64;
#pragma unroll
    for (int tm = 0; tm < 4; ++tm) {
#pragma unroll
        for (int tn = 0; tn < 4; ++tn) {
            int col = wn * 64 + tn * 16 + col0;
#pragma unroll
            for (int r = 0; r < 4; ++r) {
                int row = rowBase + tm * 16 + quad * 4 + r;
                if (row < NN) C[(size_t)row * 128 + col] = acc[tm][tn][r];
            }
        }
    }
}

// ---------------- SpMM + epilogue (bias [+res] + BN + ReLU) ----------------

template <bool RES>
__global__ __launch_bounds__(256) void k_spmm(const float* __restrict__ t,
                                              const float* __restrict__ r,
                                              const int* __restrict__ rowptr,
                                              const int* __restrict__ deg,
                                              const int* __restrict__ col,
                                              const float* __restrict__ cfv,
                                              const float* __restrict__ dinv,
                                              const float* __restrict__ bias,
                                              const float* __restrict__ gamma,
                                              const float* __restrict__ beta,
                                              float* __restrict__ hout) {
    int lane = threadIdx.x & 63;
    int node = blockIdx.x * 4 + (threadIdx.x >> 6);
    if (node >= NN) return;
    int f = lane * 2;
    int start = rowptr[node];
    int cnt = deg[node];
    float ax = 0.f, ay = 0.f;
    for (int p = 0; p < cnt; ++p) {
        int s = col[start + p];
        float w = cfv[start + p];
        float2 v = *(const float2*)&t[(size_t)s * 128 + f];
        ax += w * v.x;
        ay += w * v.y;
    }
    float di = dinv[node];
    float2 tv = *(const float2*)&t[(size_t)node * 128 + f];
    float2 bv = *(const float2*)&bias[f];
    float cx = di * ax + di * di * tv.x + bv.x;
    float cy = di * ay + di * di * tv.y + bv.y;
    if (RES) {
        float2 rv = *(const float2*)&r[(size_t)node * 128 + f];
        cx += rv.x;
        cy += rv.y;
    }
    float2 gv = *(const float2*)&gamma[f];
    float2 ev = *(const float2*)&beta[f];
    float ox = fmaxf(cx * (BN_INV * gv.x) + ev.x, 0.f);
    float oy = fmaxf(cy * (BN_INV * gv.y) + ev.y, 0.f);
    *(float2*)&hout[(size_t)node * 128 + f] = make_float2(ox, oy);
}

// ---------------- pooling (segment max over sorted batch) ----------------

__device__ inline int lbound(const int* __restrict__ b, int v) {
    int lo = 0, hi = NN;
    while (lo < hi) {
        int mid = (lo + hi) >> 1;
        if (b[mid] < v) lo = mid + 1; else hi = mid;
    }
    return lo;
}

__global__ void k_pool(const float* __restrict__ h, const int* __restrict__ batch,
                       float* __restrict__ pooled) {
    __shared__ int sLo, sHi;
    int g = blockIdx.x >> 2;
    int ch = blockIdx.x & 3;
    if (threadIdx.x == 0) {
        sLo = lbound(batch, g);
        sHi = lbound(batch, g + 1);
    }
    __syncthreads();
    int lo = sLo, hi = sHi;
    int len = hi - lo;
    int per = (len + 3) >> 2;
    int s = lo + ch * per;
    int e = min(s + per, hi);
    float m = 0.0f;  // h >= 0 post-ReLU
    for (int i = s; i < e; ++i) m = fmaxf(m, h[(size_t)i * 128 + threadIdx.x]);
    if (s < e) atomicMax((unsigned int*)&pooled[g * 128 + threadIdx.x], __float_as_uint(m));
}

// ---------------- MLP head ----------------

__global__ void k_head(const float* __restrict__ pooled, const float* __restrict__ mW1,
                       const float* __restrict__ mb1, const float* __restrict__ mW2,
                       const float* __restrict__ mb2, float* __restrict__ out) {
    __shared__ float p[128];
    __shared__ float z[128];
    int g = blockIdx.x;
    int j = threadIdx.x;  // 128 threads
    p[j] = pooled[g * 128 + j];
    __syncthreads();
    float a = mb1[j];
#pragma unroll 8
    for (int k = 0; k < 128; ++k) a += p[k] * mW1[k * 128 + j];
    z[j] = fmaxf(a, 0.f);
    __syncthreads();
    if (j < NCLASS) {
        float o = mb2[j];
#pragma unroll 8
        for (int k = 0; k < 128; ++k) o += z[k] * mW2[k * NCLASS + j];
        out[g * NCLASS + j] = o;
    }
}

// ---------------- launcher ----------------

extern "C" void kernel_launch(void* const* d_in, const int* in_sizes, int n_in,
                              void* d_out, int out_size, void* d_ws, size_t ws_size,
                              hipStream_t stream) {
    const float* x   = (const float*)d_in[0];
    const int*   ei  = (const int*)d_in[1];
    const int* batch = (const int*)d_in[2];
    const float* W0  = (const float*)d_in[3];
    const float* b0  = (const float*)d_in[4];
    const float* g0  = (const float*)d_in[5];
    const float* be0 = (const float*)d_in[6];
    const float* Wh  = (const float*)d_in[7];
    const float* bh  = (const float*)d_in[8];
    const float* gh  = (const float*)d_in[9];
    const float* beh = (const float*)d_in[10];
    const float* Rh  = (const float*)d_in[11];
    const float* mW1 = (const float*)d_in[12];
    const float* mb1 = (const float*)d_in[13];
    const float* mW2 = (const float*)d_in[14];
    const float* mb2 = (const float*)d_in[15];
    float* out = (float*)d_out;

    char* ws = (char*)d_ws;
    size_t off = 0;
    auto alloc = [&](size_t bytes) -> void* {
        void* p = ws + off;
        off += (bytes + 255) & ~(size_t)255;
        return p;
    };
    int*   deg    = (int*)alloc((size_t)NN * 4);
    int*   rowptr = (int*)alloc((size_t)NN * 4);
    int*   cursor = (int*)alloc((size_t)NN * 4);
    float* dinv   = (float*)alloc((size_t)NN * 4);
    int*   bsum   = (int*)alloc(256 * 4);
    int*   col    = (int*)alloc((size_t)NE * 4);
    float* cfv    = (float*)alloc((size_t)NE * 4);
    float* t      = (float*)alloc((size_t)NN * HID * 4);
    float* rbuf   = (float*)alloc((size_t)NN * HID * 4);
    float* hA     = (float*)alloc((size_t)NN * HID * 4);
    float* hB     = (float*)alloc((size_t)NN * HID * 4);
    float* pooled = (float*)alloc((size_t)NGRAPH * HID * 4);
    // swizzled bf16 operands
    unsigned short* ahi  = (unsigned short*)alloc((size_t)ROWBLK_PAD * 4 * 512 * 2);
    unsigned short* alo  = (unsigned short*)alloc((size_t)ROWBLK_PAD * 4 * 512 * 2);
    unsigned short* bswH = (unsigned short*)alloc((size_t)7 * 16384 * 2);
    unsigned short* bswL = (unsigned short*)alloc((size_t)7 * 16384 * 2);

    hipMemsetAsync(deg, 0, (size_t)NN * 4, stream);
    hipMemsetAsync(cursor, 0, (size_t)NN * 4, stream);
    hipMemsetAsync(pooled, 0, (size_t)NGRAPH * HID * 4, stream);

    k_deg<<<NE / 256, 256, 0, stream>>>(ei, deg);
    k_dinv<<<(NN + 255) / 256, 256, 0, stream>>>(deg, dinv);
    k_scan1<<<(NN + 255) / 256, 256, 0, stream>>>(deg, bsum);
    k_scan2<<<1, 64, 0, stream>>>(bsum, (NN + 255) / 256);
    k_scan3<<<(NN + 255) / 256, 256, 0, stream>>>(deg, bsum, rowptr);
    k_fill<<<NE / 256, 256, 0, stream>>>(ei, rowptr, cursor, dinv, col, cfv);

    k_convB<<<dim3(8, 7), 256, 0, stream>>>(W0, Wh, Rh, bswH, bswL);

    const int spmmGrid = (NN + 3) / 4;

    // initial block: t = x @ W0 ; hA = bn_relu(agg(t) + b0)
    k_convA<<<3125, 256, 0, stream>>>(x, ahi, alo);
    k_gemm_mfma<<<GEMM_GRID, 256, 0, stream>>>(ahi, alo, bswH, bswL, t);
    k_spmm<false><<<spmmGrid, 256, 0, stream>>>(t, nullptr, rowptr, deg, col, cfv,
                                                dinv, b0, g0, be0, hA);

    // residual blocks
    float* bufs[2] = {hA, hB};
    int cur = 0;
    for (int i = 0; i < LHID; ++i) {
        const float* hin = bufs[cur];
        float* hout = bufs[cur ^ 1];
        k_convA<<<3125, 256, 0, stream>>>(hin, ahi, alo);
        k_gemm_mfma<<<GEMM_GRID, 256, 0, stream>>>(
            ahi, alo, bswH + (size_t)(1 + i) * 16384, bswL + (size_t)(1 + i) * 16384, t);
        k_gemm_mfma<<<GEMM_GRID, 256, 0, stream>>>(
            ahi, alo, bswH + (size_t)(4 + i) * 16384, bswL + (size_t)(4 + i) * 16384, rbuf);
        k_spmm<true><<<spmmGrid, 256, 0, stream>>>(t, rbuf, rowptr, deg, col, cfv,
                                                   dinv, bh + i * HID, gh + i * HID,
                                                   beh + i * HID, hout);
        cur ^= 1;
    }

    k_pool<<<NGRAPH * 4, 128, 0, stream>>>(bufs[cur], batch, pooled);
    k_head<<<NGRAPH, 128, 0, stream>>>(pooled, mW1, mb1, mW2, mb2, out);
}

// Round 3
// 620.837 us; speedup vs baseline: 1.5022x; 1.1835x over previous
//
#include <hip/hip_runtime.h>
#include <cstdint>
#include <cstddef>

#define NN 50000
#define NE 800000
#define NEPAD (NE + 3 * NN)  // CSR rows padded to multiple of 4
#define HID 128
#define NGRAPH 64
#define NCLASS 10
#define LHID 3

// row-blocks of 16 rows: 50000/16 = 3125 exact; GEMM grid covers 391*8 = 3128
#define ROWBLK 3125
#define ROWBLK_PAD 3128
#define GEMM_GRID 391

// 1/sqrt(1+1e-5), computed in double, rounded to f32
static constexpr float BN_INV = 0.9999950000374996f;

typedef __attribute__((ext_vector_type(8))) __bf16 bf16x8;
typedef __attribute__((ext_vector_type(4))) float floatx4;

// ---------------- bf16 split helpers ----------------

__device__ __forceinline__ unsigned short f32_to_bf16_rne(float f) {
    unsigned int u = __float_as_uint(f);
    unsigned int r = (u + 0x7FFFu + ((u >> 16) & 1u)) >> 16;
    return (unsigned short)r;
}
__device__ __forceinline__ float bf16_to_f32(unsigned short h) {
    return __uint_as_float(((unsigned int)h) << 16);
}

__device__ __forceinline__ void gl2lds16(const void* g, void* l) {
    __builtin_amdgcn_global_load_lds((__attribute__((address_space(1))) void*)g,
                                     (__attribute__((address_space(3))) void*)l,
                                     16, 0, 0);
}

// ---------------- graph build ----------------

__global__ void k_deg(const int* __restrict__ ei, int* __restrict__ deg) {
    int e = blockIdx.x * 256 + threadIdx.x;
    if (e < NE) atomicAdd(&deg[ei[NE + e]], 1);
}

__global__ void k_dinv(const int* __restrict__ deg, float* __restrict__ dinv) {
    int i = blockIdx.x * 256 + threadIdx.x;
    if (i < NN) dinv[i] = rsqrtf((float)(deg[i] + 1));  // +1 self-loop
}

// scans over padded degree deg4 = (deg+3)&~3 so every CSR row start is 16B-aligned

__global__ void k_scan1(const int* __restrict__ deg, int* __restrict__ bsum) {
    __shared__ int s[256];
    int i = blockIdx.x * 256 + threadIdx.x;
    s[threadIdx.x] = (i < NN) ? ((deg[i] + 3) & ~3) : 0;
    __syncthreads();
    for (int o = 128; o > 0; o >>= 1) {
        if (threadIdx.x < o) s[threadIdx.x] += s[threadIdx.x + o];
        __syncthreads();
    }
    if (threadIdx.x == 0) bsum[blockIdx.x] = s[0];
}

__global__ void k_scan2(int* __restrict__ bsum, int nb) {
    if (threadIdx.x == 0 && blockIdx.x == 0) {
        int run = 0;
        for (int b = 0; b < nb; ++b) { int v = bsum[b]; bsum[b] = run; run += v; }
    }
}

__global__ void k_scan3(const int* __restrict__ deg, const int* __restrict__ bsum,
                        int* __restrict__ rowptr) {
    __shared__ int s[256];
    int i = blockIdx.x * 256 + threadIdx.x;
    int v = (i < NN) ? ((deg[i] + 3) & ~3) : 0;
    s[threadIdx.x] = v;
    __syncthreads();
    for (int o = 1; o < 256; o <<= 1) {
        int tv = (threadIdx.x >= o) ? s[threadIdx.x - o] : 0;
        __syncthreads();
        s[threadIdx.x] += tv;
        __syncthreads();
    }
    if (i < NN) rowptr[i] = bsum[blockIdx.x] + s[threadIdx.x] - v;  // exclusive
}

__global__ void k_fill(const int* __restrict__ ei, const int* __restrict__ rowptr,
                       int* __restrict__ cursor, const float* __restrict__ dinv,
                       int* __restrict__ col, float* __restrict__ cfv) {
    int e = blockIdx.x * 256 + threadIdx.x;
    if (e >= NE) return;
    int s = ei[e];
    int d = ei[NE + e];
    int p = rowptr[d] + atomicAdd(&cursor[d], 1);
    col[p] = s;
    cfv[p] = dinv[s];
}

// ---------------- converters: fp32 -> swizzled bf16 hi/lo ----------------
// A-operand fragment layout per (rowBlock of 16 m) x (kblk of 32 k) block:
//   lane = ((k>>3)&3)*16 + (m&15), holds 8 consecutive k (16 B).
// Flat: ((rowBlock*4 + kblk)*64 + lane)*8 elements.

__global__ void k_convA(const float* __restrict__ src, unsigned short* __restrict__ hi,
                        unsigned short* __restrict__ lo) {
    int u = blockIdx.x * 256 + threadIdx.x;  // 0 .. 800000-1 (one 16B output unit each)
    int lane = u & 63;
    int blk = u >> 6;
    int kblk = blk & 3;
    int rowBlock = blk >> 2;
    int m = rowBlock * 16 + (lane & 15);
    int k = kblk * 32 + (lane >> 4) * 8;
    const float4* p = (const float4*)&src[(size_t)m * 128 + k];
    float4 v0 = p[0];
    float4 v1 = p[1];
    float vals[8] = {v0.x, v0.y, v0.z, v0.w, v1.x, v1.y, v1.z, v1.w};
    union { unsigned short s[8]; uint4 v; } H, L;
#pragma unroll
    for (int j = 0; j < 8; ++j) {
        unsigned short h = f32_to_bf16_rne(vals[j]);
        H.s[j] = h;
        L.s[j] = f32_to_bf16_rne(vals[j] - bf16_to_f32(h));
    }
    *(uint4*)&hi[(size_t)u * 8] = H.v;
    *(uint4*)&lo[(size_t)u * 8] = L.v;
}

// B-operand: source W is [k][n] row-major (128x128). Fragment layout per
// (nBlock of 16 n) x (kblk of 32 k): lane = ((k>>3)&3)*16 + (n&15), 8 consecutive k.
// 7 matrices: 0 = W0, 1..3 = Wh[i], 4..6 = Rh[i]; each 16384 elems in output.

__global__ void k_convB(const float* __restrict__ W0, const float* __restrict__ Wh,
                        const float* __restrict__ Rh, unsigned short* __restrict__ hi,
                        unsigned short* __restrict__ lo) {
    int mat = blockIdx.y;
    const float* src = (mat == 0) ? W0
                     : (mat <= 3) ? (Wh + (size_t)(mat - 1) * 16384)
                                  : (Rh + (size_t)(mat - 4) * 16384);
    int u = blockIdx.x * 256 + threadIdx.x;  // 0..2047
    int lane = u & 63;
    int blk = u >> 6;
    int kblk = blk & 3;
    int nb = blk >> 2;
    int n = nb * 16 + (lane & 15);
    int k = kblk * 32 + (lane >> 4) * 8;
    union { unsigned short s[8]; uint4 v; } H, L;
#pragma unroll
    for (int j = 0; j < 8; ++j) {
        float f = src[(size_t)(k + j) * 128 + n];
        unsigned short h = f32_to_bf16_rne(f);
        H.s[j] = h;
        L.s[j] = f32_to_bf16_rne(f - bf16_to_f32(h));
    }
    size_t base = (size_t)mat * 16384 + (size_t)u * 8;
    *(uint4*)&hi[base] = H.v;
    *(uint4*)&lo[base] = L.v;
}

// ---------------- MFMA GEMM: C = A @ B, split-bf16 3-product ----------------

__global__ __launch_bounds__(256, 2) void k_gemm_mfma(
    const unsigned short* __restrict__ Ahi, const unsigned short* __restrict__ Alo,
    const unsigned short* __restrict__ Bhi, const unsigned short* __restrict__ Blo,
    float* __restrict__ C) {
    __shared__ unsigned short lds[4 * 8192];  // 64 KB
    unsigned short* AhiS = lds;
    unsigned short* AloS = lds + 8192;
    unsigned short* BhiS = lds + 16384;
    unsigned short* BloS = lds + 24576;

    const int tid = threadIdx.x;
    const int wave = tid >> 6;
    const int lane = tid & 63;
    const int wm = wave & 1;
    const int wn = wave >> 1;
    const int rb0 = blockIdx.x * 8;

    floatx4 acc[4][4];
    floatx4 zero = {0.f, 0.f, 0.f, 0.f};
#pragma unroll
    for (int i = 0; i < 4; ++i)
#pragma unroll
        for (int j = 0; j < 4; ++j) acc[i][j] = zero;

    for (int kc = 0; kc < 2; ++kc) {
#pragma unroll
        for (int it = 0; it < 4; ++it) {
            int b = it * 4 + wave;        // 0..15 : rb = b>>1, kb = b&1
            int rb = b >> 1;
            int kb = b & 1;
            size_t aOff = ((size_t)(rb0 + rb) * 4 + kc * 2 + kb) * 512 + (size_t)lane * 8;
            size_t bOff = ((size_t)rb * 4 + kc * 2 + kb) * 512 + (size_t)lane * 8;
            int ldsOff = b * 512;  // wave-uniform base; HW adds lane*16B
            gl2lds16(Ahi + aOff, AhiS + ldsOff);
            gl2lds16(Alo + aOff, AloS + ldsOff);
            gl2lds16(Bhi + bOff, BhiS + ldsOff);
            gl2lds16(Blo + bOff, BloS + ldsOff);
        }
        __syncthreads();

#pragma unroll
        for (int kb = 0; kb < 2; ++kb) {
            bf16x8 aH[4], aL[4], bH[4], bL[4];
#pragma unroll
            for (int t = 0; t < 4; ++t) {
                aH[t] = *(const bf16x8*)(AhiS + ((wm * 4 + t) * 2 + kb) * 512 + lane * 8);
                bH[t] = *(const bf16x8*)(BhiS + ((wn * 4 + t) * 2 + kb) * 512 + lane * 8);
            }
#pragma unroll
            for (int tm = 0; tm < 4; ++tm)
#pragma unroll
                for (int tn = 0; tn < 4; ++tn)
                    acc[tm][tn] = __builtin_amdgcn_mfma_f32_16x16x32_bf16(
                        aH[tm], bH[tn], acc[tm][tn], 0, 0, 0);
#pragma unroll
            for (int t = 0; t < 4; ++t)
                bL[t] = *(const bf16x8*)(BloS + ((wn * 4 + t) * 2 + kb) * 512 + lane * 8);
#pragma unroll
            for (int tm = 0; tm < 4; ++tm)
#pragma unroll
                for (int tn = 0; tn < 4; ++tn)
                    acc[tm][tn] = __builtin_amdgcn_mfma_f32_16x16x32_bf16(
                        aH[tm], bL[tn], acc[tm][tn], 0, 0, 0);
#pragma unroll
            for (int t = 0; t < 4; ++t)
                aL[t] = *(const bf16x8*)(AloS + ((wm * 4 + t) * 2 + kb) * 512 + lane * 8);
#pragma unroll
            for (int tm = 0; tm < 4; ++tm)
#pragma unroll
                for (int tn = 0; tn < 4; ++tn)
                    acc[tm][tn] = __builtin_amdgcn_mfma_f32_16x16x32_bf16(
                        aL[tm], bH[tn], acc[tm][tn], 0, 0, 0);
        }
        __syncthreads();
    }

    // epilogue: C/D layout col = lane&15, row = (lane>>4)*4 + r
    const int quad = lane >> 4;
    const int col0 = lane & 15;
    const int rowBase = rb0 * 16 + wm * 64;
#pragma unroll
    for (int tm = 0; tm < 4; ++tm) {
#pragma unroll
        for (int tn = 0; tn < 4; ++tn) {
            int col = wn * 64 + tn * 16 + col0;
#pragma unroll
            for (int r = 0; r < 4; ++r) {
                int row = rowBase + tm * 16 + quad * 4 + r;
                if (row < NN) C[(size_t)row * 128 + col] = acc[tm][tn][r];
            }
        }
    }
}

// ---------------- SpMM + epilogue (bias [+res] + BN + ReLU) ----------------
// one wave per node; lane handles 2 features (float2). CSR rows padded to
// multiples of 4 (cfv=0 in pad slots) -> metadata loads are int4/float4 and
// 4 row-gathers are independent/in-flight per iteration.

template <bool RES>
__global__ __launch_bounds__(256) void k_spmm(const float* __restrict__ t,
                                              const float* __restrict__ r,
                                              const int* __restrict__ rowptr,
                                              const int* __restrict__ deg,
                                              const int* __restrict__ col,
                                              const float* __restrict__ cfv,
                                              const float* __restrict__ dinv,
                                              const float* __restrict__ bias,
                                              const float* __restrict__ gamma,
                                              const float* __restrict__ beta,
                                              float* __restrict__ hout) {
    int lane = threadIdx.x & 63;
    int node = blockIdx.x * 4 + (threadIdx.x >> 6);
    if (node >= NN) return;
    int f = lane * 2;
    int start = rowptr[node];          // multiple of 4 -> 16B-aligned metadata
    int cnt4 = (deg[node] + 3) >> 2;
    float ax = 0.f, ay = 0.f;
#pragma unroll 2
    for (int q = 0; q < cnt4; ++q) {
        int4 cs = *(const int4*)&col[start + q * 4];
        float4 wv = *(const float4*)&cfv[start + q * 4];
        float2 v0 = *(const float2*)&t[(size_t)cs.x * 128 + f];
        float2 v1 = *(const float2*)&t[(size_t)cs.y * 128 + f];
        float2 v2 = *(const float2*)&t[(size_t)cs.z * 128 + f];
        float2 v3 = *(const float2*)&t[(size_t)cs.w * 128 + f];
        ax = fmaf(wv.x, v0.x, ax); ay = fmaf(wv.x, v0.y, ay);
        ax = fmaf(wv.y, v1.x, ax); ay = fmaf(wv.y, v1.y, ay);
        ax = fmaf(wv.z, v2.x, ax); ay = fmaf(wv.z, v2.y, ay);
        ax = fmaf(wv.w, v3.x, ax); ay = fmaf(wv.w, v3.y, ay);
    }
    float di = dinv[node];
    float2 tv = *(const float2*)&t[(size_t)node * 128 + f];
    float2 bv = *(const float2*)&bias[f];
    float cx = di * ax + di * di * tv.x + bv.x;
    float cy = di * ay + di * di * tv.y + bv.y;
    if (RES) {
        float2 rv = *(const float2*)&r[(size_t)node * 128 + f];
        cx += rv.x;
        cy += rv.y;
    }
    float2 gv = *(const float2*)&gamma[f];
    float2 ev = *(const float2*)&beta[f];
    float ox = fmaxf(cx * (BN_INV * gv.x) + ev.x, 0.f);
    float oy = fmaxf(cy * (BN_INV * gv.y) + ev.y, 0.f);
    *(float2*)&hout[(size_t)node * 128 + f] = make_float2(ox, oy);
}

// ---------------- pooling (segment max over sorted batch) ----------------

__device__ inline int lbound(const int* __restrict__ b, int v) {
    int lo = 0, hi = NN;
    while (lo < hi) {
        int mid = (lo + hi) >> 1;
        if (b[mid] < v) lo = mid + 1; else hi = mid;
    }
    return lo;
}

__global__ void k_pool(const float* __restrict__ h, const int* __restrict__ batch,
                       float* __restrict__ pooled) {
    __shared__ int sLo, sHi;
    int g = blockIdx.x >> 2;
    int ch = blockIdx.x & 3;
    if (threadIdx.x == 0) {
        sLo = lbound(batch, g);
        sHi = lbound(batch, g + 1);
    }
    __syncthreads();
    int lo = sLo, hi = sHi;
    int len = hi - lo;
    int per = (len + 3) >> 2;
    int s = lo + ch * per;
    int e = min(s + per, hi);
    float m = 0.0f;  // h >= 0 post-ReLU
    for (int i = s; i < e; ++i) m = fmaxf(m, h[(size_t)i * 128 + threadIdx.x]);
    if (s < e) atomicMax((unsigned int*)&pooled[g * 128 + threadIdx.x], __float_as_uint(m));
}

// ---------------- MLP head ----------------

__global__ void k_head(const float* __restrict__ pooled, const float* __restrict__ mW1,
                       const float* __restrict__ mb1, const float* __restrict__ mW2,
                       const float* __restrict__ mb2, float* __restrict__ out) {
    __shared__ float p[128];
    __shared__ float z[128];
    int g = blockIdx.x;
    int j = threadIdx.x;  // 128 threads
    p[j] = pooled[g * 128 + j];
    __syncthreads();
    float a = mb1[j];
#pragma unroll 8
    for (int k = 0; k < 128; ++k) a += p[k] * mW1[k * 128 + j];
    z[j] = fmaxf(a, 0.f);
    __syncthreads();
    if (j < NCLASS) {
        float o = mb2[j];
#pragma unroll 8
        for (int k = 0; k < 128; ++k) o += z[k] * mW2[k * NCLASS + j];
        out[g * NCLASS + j] = o;
    }
}

// ---------------- launcher ----------------

extern "C" void kernel_launch(void* const* d_in, const int* in_sizes, int n_in,
                              void* d_out, int out_size, void* d_ws, size_t ws_size,
                              hipStream_t stream) {
    const float* x   = (const float*)d_in[0];
    const int*   ei  = (const int*)d_in[1];
    const int* batch = (const int*)d_in[2];
    const float* W0  = (const float*)d_in[3];
    const float* b0  = (const float*)d_in[4];
    const float* g0  = (const float*)d_in[5];
    const float* be0 = (const float*)d_in[6];
    const float* Wh  = (const float*)d_in[7];
    const float* bh  = (const float*)d_in[8];
    const float* gh  = (const float*)d_in[9];
    const float* beh = (const float*)d_in[10];
    const float* Rh  = (const float*)d_in[11];
    const float* mW1 = (const float*)d_in[12];
    const float* mb1 = (const float*)d_in[13];
    const float* mW2 = (const float*)d_in[14];
    const float* mb2 = (const float*)d_in[15];
    float* out = (float*)d_out;

    char* ws = (char*)d_ws;
    size_t off = 0;
    auto alloc = [&](size_t bytes) -> void* {
        void* p = ws + off;
        off += (bytes + 255) & ~(size_t)255;
        return p;
    };
    int*   deg    = (int*)alloc((size_t)NN * 4);
    int*   rowptr = (int*)alloc((size_t)NN * 4);
    int*   cursor = (int*)alloc((size_t)NN * 4);
    float* dinv   = (float*)alloc((size_t)NN * 4);
    int*   bsum   = (int*)alloc(256 * 4);
    int*   col    = (int*)alloc((size_t)NEPAD * 4);
    float* cfv    = (float*)alloc((size_t)NEPAD * 4);
    float* t      = (float*)alloc((size_t)NN * HID * 4);
    float* rbuf   = (float*)alloc((size_t)NN * HID * 4);
    float* hA     = (float*)alloc((size_t)NN * HID * 4);
    float* hB     = (float*)alloc((size_t)NN * HID * 4);
    float* pooled = (float*)alloc((size_t)NGRAPH * HID * 4);
    // swizzled bf16 operands
    unsigned short* ahi  = (unsigned short*)alloc((size_t)ROWBLK_PAD * 4 * 512 * 2);
    unsigned short* alo  = (unsigned short*)alloc((size_t)ROWBLK_PAD * 4 * 512 * 2);
    unsigned short* bswH = (unsigned short*)alloc((size_t)7 * 16384 * 2);
    unsigned short* bswL = (unsigned short*)alloc((size_t)7 * 16384 * 2);

    hipMemsetAsync(deg, 0, (size_t)NN * 4, stream);
    hipMemsetAsync(cursor, 0, (size_t)NN * 4, stream);
    hipMemsetAsync(pooled, 0, (size_t)NGRAPH * HID * 4, stream);
    hipMemsetAsync(col, 0, (size_t)NEPAD * 4, stream);
    hipMemsetAsync(cfv, 0, (size_t)NEPAD * 4, stream);

    k_deg<<<NE / 256, 256, 0, stream>>>(ei, deg);
    k_dinv<<<(NN + 255) / 256, 256, 0, stream>>>(deg, dinv);
    k_scan1<<<(NN + 255) / 256, 256, 0, stream>>>(deg, bsum);
    k_scan2<<<1, 64, 0, stream>>>(bsum, (NN + 255) / 256);
    k_scan3<<<(NN + 255) / 256, 256, 0, stream>>>(deg, bsum, rowptr);
    k_fill<<<NE / 256, 256, 0, stream>>>(ei, rowptr, cursor, dinv, col, cfv);

    k_convB<<<dim3(8, 7), 256, 0, stream>>>(W0, Wh, Rh, bswH, bswL);

    const int spmmGrid = (NN + 3) / 4;

    // initial block: t = x @ W0 ; hA = bn_relu(agg(t) + b0)
    k_convA<<<3125, 256, 0, stream>>>(x, ahi, alo);
    k_gemm_mfma<<<GEMM_GRID, 256, 0, stream>>>(ahi, alo, bswH, bswL, t);
    k_spmm<false><<<spmmGrid, 256, 0, stream>>>(t, nullptr, rowptr, deg, col, cfv,
                                                dinv, b0, g0, be0, hA);

    // residual blocks
    float* bufs[2] = {hA, hB};
    int cur = 0;
    for (int i = 0; i < LHID; ++i) {
        const float* hin = bufs[cur];
        float* hout = bufs[cur ^ 1];
        k_convA<<<3125, 256, 0, stream>>>(hin, ahi, alo);
        k_gemm_mfma<<<GEMM_GRID, 256, 0, stream>>>(
            ahi, alo, bswH + (size_t)(1 + i) * 16384, bswL + (size_t)(1 + i) * 16384, t);
        k_gemm_mfma<<<GEMM_GRID, 256, 0, stream>>>(
            ahi, alo, bswH + (size_t)(4 + i) * 16384, bswL + (size_t)(4 + i) * 16384, rbuf);
        k_spmm<true><<<spmmGrid, 256, 0, stream>>>(t, rbuf, rowptr, deg, col, cfv,
                                                   dinv, bh + i * HID, gh + i * HID,
                                                   beh + i * HID, hout);
        cur ^= 1;
    }

    k_pool<<<NGRAPH * 4, 128, 0, stream>>>(bufs[cur], batch, pooled);
    k_head<<<NGRAPH, 128, 0, stream>>>(pooled, mW1, mb1, mW2, mb2, out);
}